// Round 5
// baseline (64.167 us; speedup 1.0000x reference)
//
#include <hip/hip_runtime.h>

// Problem constants (from reference)
#define NQ 6
#define DD 64            // 2^NQ
#define NF 4
#define GG 14
#define GG2 196
#define GG3 2744
#define NSIDE 12
#define PP 1728          // NSIDE^3
#define NC 40
#define BB 16
#define LAM 0.1f
#define FEAT_LEN (NF*PP*NQ)   // 41472
#define KCH 512
#define NCHUNK 81             // 41472 / 512
#define CTILES 5              // 40 / 8

// ---------- helpers ----------

// First column (u00,u10) of PennyLane Rot(phi,th,om)
__device__ __forceinline__ void rotcol(float phi, float th, float om,
    float& c0r, float& c0i, float& c1r, float& c1i)
{
    float s, c, sap, cap, sam, cam;
    __sincosf(0.5f*th, &s, &c);
    __sincosf(0.5f*(phi+om), &sap, &cap);
    __sincosf(0.5f*(phi-om), &sam, &cam);
    c0r = cap*c; c0i = -sap*c;
    c1r = cam*s; c1i = -sam*s;
}

// Local sparse spread ladder: 32-amp local state, support = multiples of
// 2*MASK, only first gate column needed. 16/MASK pairs, 8 ops each.
template<int MASK>
__device__ __forceinline__ void spreadL(float* sr, float* si,
    float c0r, float c0i, float c1r, float c1i)
{
    #pragma unroll
    for (int i = 0; i < 16/MASK; ++i) {
        const int d0 = i*2*MASK, d1 = d0 + MASK;
        float a0r = sr[d0], a0i = si[d0];
        sr[d1] = c1r*a0r - c1i*a0i;
        si[d1] = c1r*a0i + c1i*a0r;
        sr[d0] = c0r*a0r - c0i*a0i;
        si[d0] = c0r*a0i + c0i*a0r;
    }
}

// Full 1q gate on local bit TMASK (16 pairs over 32 local amps)
template<int TMASK>
__device__ __forceinline__ void gate1L(float* sr, float* si, float4 A, float4 Bq)
{
    #pragma unroll
    for (int d0 = 0; d0 < 32; ++d0) {
        if (d0 & TMASK) continue;
        const int d1 = d0 | TMASK;
        float a0r = sr[d0], a0i = si[d0];
        float a1r = sr[d1], a1i = si[d1];
        sr[d0] = A.x*a0r - A.y*a0i + A.z*a1r - A.w*a1i;
        si[d0] = A.x*a0i + A.y*a0r + A.z*a1i + A.w*a1r;
        sr[d1] = Bq.x*a0r - Bq.y*a0i + Bq.z*a1r - Bq.w*a1i;
        si[d1] = Bq.x*a0i + Bq.y*a0r + Bq.z*a1i + Bq.w*a1r;
    }
}

// Local controlled Rot (control & target both local bits)
template<int CMASK, int TMASK>
__device__ __forceinline__ void crotL(float* sr, float* si, float4 A, float4 Bq)
{
    #pragma unroll
    for (int d0 = 0; d0 < 32; ++d0) {
        if (!(d0 & CMASK) || (d0 & TMASK)) continue;
        const int d1 = d0 | TMASK;
        float a0r = sr[d0], a0i = si[d0];
        float a1r = sr[d1], a1i = si[d1];
        sr[d0] = A.x*a0r - A.y*a0i + A.z*a1r - A.w*a1i;
        si[d0] = A.x*a0i + A.y*a0r + A.z*a1i + A.w*a1r;
        sr[d1] = Bq.x*a0r - Bq.y*a0i + Bq.z*a1r - Bq.w*a1i;
        si[d1] = Bq.x*a0i + Bq.y*a0r + Bq.z*a1i + Bq.w*a1r;
    }
}

// ---------- sim: 2 threads per circuit (h = state bit 5); block = 1 patch ----------

__global__ __launch_bounds__(128, 4) void sim_kernel(
    const float* __restrict__ x,      // [B,14,14,14]
    const float* __restrict__ theta,  // [NF,1,6,3]
    float* __restrict__ feats,        // [B][NF][PP][NQ]
    float* __restrict__ ip2)          // [PP][2]
{
    const int p = blockIdx.x;
    const int t = threadIdx.x;        // 128 threads = 2 waves
    const int w = t >> 6;
    const int lane = t & 63;
    const int b = t >> 3;             // 0..15 (b = w*8 + lane>>3)
    const int f = (lane >> 1) & 3;
    const int h = lane & 1;           // state bit 5

    __shared__ __align__(16) float scrot[NF*NQ][8];
    if (t < NF*NQ) {
        const float* a = theta + t*3;
        float s, c, sap, cap, sam, cam;
        __sincosf(0.5f*a[1], &s, &c);
        __sincosf(0.5f*(a[0]+a[2]), &sap, &cap);
        __sincosf(0.5f*(a[0]-a[2]), &sam, &cam);
        scrot[t][0] =  cap*c; scrot[t][1] = -sap*c;
        scrot[t][2] = -cam*s; scrot[t][3] = -sam*s;
        scrot[t][4] =  cam*s; scrot[t][5] = -sam*s;
        scrot[t][6] =  cap*c; scrot[t][7] =  sap*c;
    }
    __syncthreads();

    const int px = p/(NSIDE*NSIDE), py = (p/NSIDE)%NSIDE, pz = p%NSIDE;
    const float* xp = x + (size_t)b*GG3 + px*GG2 + py*GG + pz;
    #define SPV(i) xp[((i)/9)*GG2 + (((i)/3)%3)*GG + ((i)%3)]

    float sr[32], si[32];

    // ---- encoding. qubit q <-> global bit 5-q. h carries bit5 (qubit0).
    // Composed first-column per qubit: q<3 -> gates (q, q+6); q>=3 -> gate q.

    // qubit0 (bit5 = h): composed column, local amp[0] = col[h]
    {
        float a0r,a0i,a1r,a1i;
        rotcol(SPV(0), SPV(1), SPV(2), a0r,a0i,a1r,a1i);
        float s_,c_,sap_,cap_,sam_,cam_;
        __sincosf(0.5f*SPV(19), &s_, &c_);
        __sincosf(0.5f*(SPV(18)+SPV(20)), &sap_, &cap_);
        __sincosf(0.5f*(SPV(18)-SPV(20)), &sam_, &cam_);
        float b00r=cap_*c_, b00i=-sap_*c_, b01r=-cam_*s_, b01i=-sam_*s_;
        float b10r=cam_*s_, b10i=-sam_*s_, b11r=cap_*c_,  b11i= sap_*c_;
        float c0r = b00r*a0r - b00i*a0i + b01r*a1r - b01i*a1i;
        float c0i = b00r*a0i + b00i*a0r + b01r*a1i + b01i*a1r;
        float c1r = b10r*a0r - b10i*a0i + b11r*a1r - b11i*a1i;
        float c1i = b10r*a0i + b10i*a0r + b11r*a1i + b11i*a1r;
        sr[0] = h ? c1r : c0r;
        si[0] = h ? c1i : c0i;
    }

    // qubits 1,2: composed column + local spread (masks 16, 8)
    #define ENC2(Q, MASK) { \
        float a0r,a0i,a1r,a1i; \
        rotcol(SPV(3*(Q)), SPV(3*(Q)+1), SPV(3*(Q)+2), a0r,a0i,a1r,a1i); \
        const int K2 = 3*((Q)+6); \
        float s_,c_,sap_,cap_,sam_,cam_; \
        __sincosf(0.5f*SPV(K2+1), &s_, &c_); \
        __sincosf(0.5f*(SPV(K2)+SPV(K2+2)), &sap_, &cap_); \
        __sincosf(0.5f*(SPV(K2)-SPV(K2+2)), &sam_, &cam_); \
        float b00r=cap_*c_, b00i=-sap_*c_, b01r=-cam_*s_, b01i=-sam_*s_; \
        float b10r=cam_*s_, b10i=-sam_*s_, b11r=cap_*c_,  b11i= sap_*c_; \
        float c0r = b00r*a0r - b00i*a0i + b01r*a1r - b01i*a1i; \
        float c0i = b00r*a0i + b00i*a0r + b01r*a1i + b01i*a1r; \
        float c1r = b10r*a0r - b10i*a0i + b11r*a1r - b11i*a1i; \
        float c1i = b10r*a0i + b10i*a0r + b11r*a1i + b11i*a1r; \
        spreadL<MASK>(sr, si, c0r, c0i, c1r, c1i); }

    #define ENC1(Q, MASK) { \
        float c0r,c0i,c1r,c1i; \
        rotcol(SPV(3*(Q)), SPV(3*(Q)+1), SPV(3*(Q)+2), c0r,c0i,c1r,c1i); \
        spreadL<MASK>(sr, si, c0r, c0i, c1r, c1i); }

    ENC2(1, 16) ENC2(2, 8)
    ENC1(3, 4)  ENC1(4, 2)  ENC1(5, 1)
    #undef ENC2
    #undef ENC1
    #undef SPV

    // ---- CRot layer for feature f: control qubit i -> target qubit (i+1)%6
    // CR0: ctrl bit5(h), tgt local 16: only h=1 lanes apply (local gate)
    {
        float4 A  = *(const float4*)&scrot[f*NQ + 0][0];
        float4 Bq = *(const float4*)&scrot[f*NQ + 0][4];
        if (h) gate1L<16>(sr, si, A, Bq);
    }
    // CR1..CR4: fully local
    #define CRL(I, CM, TM) { \
        float4 A  = *(const float4*)&scrot[f*NQ + (I)][0]; \
        float4 Bq = *(const float4*)&scrot[f*NQ + (I)][4]; \
        crotL<CM, TM>(sr, si, A, Bq); }
    CRL(1, 16, 8) CRL(2, 8, 4) CRL(3, 4, 2) CRL(4, 2, 1)
    #undef CRL
    // CR5: ctrl local bit0, tgt bit5(h): cross-pair exchange with lane^1
    {
        float4 A  = *(const float4*)&scrot[f*NQ + 5][0];
        float4 Bq = *(const float4*)&scrot[f*NQ + 5][4];
        float cAr = h ? Bq.z : A.x, cAi = h ? Bq.w : A.y;   // coef on own amp
        float cBr = h ? Bq.x : A.z, cBi = h ? Bq.y : A.w;   // coef on partner
        #pragma unroll
        for (int d = 1; d < 32; d += 2) {
            float pr_ = __shfl_xor(sr[d], 1);
            float pi_ = __shfl_xor(si[d], 1);
            float nr = cAr*sr[d] - cAi*si[d] + cBr*pr_ - cBi*pi_;
            float ni = cAr*si[d] + cAi*sr[d] + cBr*pi_ + cBi*pr_;
            sr[d] = nr; si[d] = ni;
        }
    }

    // ---- probabilities overwrite sr (si dead)
    #pragma unroll
    for (int d = 0; d < 32; ++d) sr[d] = sr[d]*sr[d] + si[d]*si[d];

    // ---- loss pair-dots: f-partners at lane^2,^4,^6 (same h), combine over h
    float lsum = 0.f;
    #pragma unroll
    for (int xm = 2; xm <= 6; xm += 2) {
        float partial = 0.f;
        #pragma unroll
        for (int d = 0; d < 32; ++d)
            partial += sr[d] * __shfl_xor(sr[d], xm);
        float dot = partial + __shfl_xor(partial, 1);
        lsum += dot*dot;
    }
    #pragma unroll
    for (int m = 1; m < 64; m <<= 1) lsum += __shfl_xor(lsum, m);
    if (lane == 0) ip2[p*2 + w] = lsum;

    // ---- expvals: local signed tree (qubits 5..1), then h-combine; qubit0 from h
    float ev[NQ];
    #pragma unroll
    for (int lvl = 0; lvl < 5; ++lvl) {
        const int n = 32 >> (lvl + 1);
        float diff = 0.f;
        #pragma unroll
        for (int i = 0; i < n; ++i) diff += sr[2*i] - sr[2*i+1];
        ev[5 - lvl] = diff;
        #pragma unroll
        for (int i = 0; i < n; ++i) sr[i] = sr[2*i] + sr[2*i+1];
    }
    ev[0] = h ? -sr[0] : sr[0];
    #pragma unroll
    for (int q = 0; q < NQ; ++q) ev[q] += __shfl_xor(ev[q], 1);

    float* fo = feats + (((size_t)b*NF + f)*PP + p)*NQ + 3*h;
    fo[0] = ev[3*h]; fo[1] = ev[3*h+1]; fo[2] = ev[3*h+2];
}

// ---------- logits phase A: K-split, W read once ----------

__global__ __launch_bounds__(128) void logitsA(
    const float* __restrict__ feats,   // [BB][FEAT_LEN]
    const float* __restrict__ W,       // [NC][FEAT_LEN]
    float* __restrict__ partial)       // [NC][BB][NCHUNK]
{
    const int chunk = blockIdx.x;      // 0..80
    const int ctile = blockIdx.y;      // 0..4
    const int t = threadIdx.x;         // 128
    const int jbase = chunk * KCH;

    __shared__ __align__(16) float fs[BB][KCH + 4];

    #pragma unroll
    for (int i = 0; i < 16; ++i) {
        const int gi = i*128 + t;
        const int br = gi >> 7;
        const int c4 = gi & 127;
        float4 v = *(const float4*)(feats + (size_t)br*FEAT_LEN + jbase + c4*4);
        *(float4*)&fs[br][c4*4] = v;
    }
    __syncthreads();

    const int cl = t >> 4, b = t & 15;
    const int c = ctile*8 + cl;
    const float* wr = W + (size_t)c*FEAT_LEN + jbase;
    float acc = 0.f;
    #pragma unroll 8
    for (int j4 = 0; j4 < KCH/4; ++j4) {
        float4 wv = *(const float4*)(wr + j4*4);
        float4 fv = *(const float4*)&fs[b][j4*4];
        acc += wv.x*fv.x + wv.y*fv.y + wv.z*fv.z + wv.w*fv.w;
    }
    partial[((size_t)c*BB + b)*NCHUNK + chunk] = acc;
}

// ---------- phase B: logits reduce + bias, and loss reduce ----------

__global__ __launch_bounds__(768) void finalize_kernel(
    const float* __restrict__ partial, const float* __restrict__ bias,
    const float* __restrict__ ip2, float* __restrict__ out)
{
    const int t = threadIdx.x;
    if (t < BB*NC) {
        const int b = t / NC, c = t % NC;
        const float* pp = partial + ((size_t)c*BB + b)*NCHUNK;
        float acc = bias[c];
        #pragma unroll 27
        for (int i = 0; i < NCHUNK; ++i) acc += pp[i];
        out[t] = acc;
    } else if (t >= 704) {
        const int lane = t - 704;
        float acc = 0.f;
        for (int i = lane; i < PP*2; i += 64) acc += ip2[i];
        #pragma unroll
        for (int m = 1; m < 64; m <<= 1) acc += __shfl_xor(acc, m);
        if (lane == 0)   // extra /2: each unordered dot counted once per h-lane
            out[BB*NC] = acc * (LAM / (float)(NF*(NF-1)) / (float)BB * 0.5f);
    }
}

extern "C" void kernel_launch(void* const* d_in, const int* in_sizes, int n_in,
                              void* d_out, int out_size, void* d_ws, size_t ws_size,
                              hipStream_t stream) {
    const float* x     = (const float*)d_in[0];  // [16,14,14,14]
    const float* theta = (const float*)d_in[1];  // [4,1,6,3]
    const float* W     = (const float*)d_in[2];  // [40,41472]
    const float* bias  = (const float*)d_in[3];  // [40]
    float* out = (float*)d_out;                  // [640 logits][1 loss]

    float* feats   = (float*)d_ws;                       // BB*FEAT_LEN
    float* ip2     = feats + (size_t)BB * FEAT_LEN;      // PP*2
    float* partial = ip2 + (size_t)PP * 2;               // NC*BB*NCHUNK

    sim_kernel<<<PP, 128, 0, stream>>>(x, theta, feats, ip2);
    logitsA<<<dim3(NCHUNK, CTILES), 128, 0, stream>>>(feats, W, partial);
    finalize_kernel<<<1, 768, 0, stream>>>(partial, bias, ip2, out);
}

// Round 6
// 50.653 us; speedup vs baseline: 1.2668x; 1.2668x over previous
//
#include <hip/hip_runtime.h>

// Problem constants (from reference)
#define NQ 6
#define DD 64            // 2^NQ
#define NF 4
#define GG 14
#define GG2 196
#define GG3 2744
#define NSIDE 12
#define PP 1728          // NSIDE^3
#define NC 40
#define BB 16
#define LAM 0.1f
#define FEAT_LEN (NF*PP*NQ)   // 41472
#define KCH 512
#define NCHUNK 81             // 41472 / 512
#define CTILES 5              // 40 / 8

// ---------- helpers ----------

// First column (u00,u10) of PennyLane Rot(phi,th,om)
__device__ __forceinline__ void rotcol(float phi, float th, float om,
    float& c0r, float& c0i, float& c1r, float& c1i)
{
    float s, c, sap, cap, sam, cam;
    __sincosf(0.5f*th, &s, &c);
    __sincosf(0.5f*(phi+om), &sap, &cap);
    __sincosf(0.5f*(phi-om), &sam, &cam);
    c0r = cap*c; c0i = -sap*c;
    c1r = cam*s; c1i = -sam*s;
}

// Local sparse spread ladder: 32-amp local state, support = multiples of
// 2*MASK, only first gate column needed.
template<int MASK>
__device__ __forceinline__ void spreadL(float* sr, float* si,
    float c0r, float c0i, float c1r, float c1i)
{
    #pragma unroll
    for (int i = 0; i < 16/MASK; ++i) {
        const int d0 = i*2*MASK, d1 = d0 + MASK;
        float a0r = sr[d0], a0i = si[d0];
        sr[d1] = c1r*a0r - c1i*a0i;
        si[d1] = c1r*a0i + c1i*a0r;
        sr[d0] = c0r*a0r - c0i*a0i;
        si[d0] = c0r*a0i + c0i*a0r;
    }
}

// Full 1q gate on local bit TMASK (16 pairs over 32 local amps)
template<int TMASK>
__device__ __forceinline__ void gate1L(float* sr, float* si, float4 A, float4 Bq)
{
    #pragma unroll
    for (int d0 = 0; d0 < 32; ++d0) {
        if (d0 & TMASK) continue;
        const int d1 = d0 | TMASK;
        float a0r = sr[d0], a0i = si[d0];
        float a1r = sr[d1], a1i = si[d1];
        sr[d0] = A.x*a0r - A.y*a0i + A.z*a1r - A.w*a1i;
        si[d0] = A.x*a0i + A.y*a0r + A.z*a1i + A.w*a1r;
        sr[d1] = Bq.x*a0r - Bq.y*a0i + Bq.z*a1r - Bq.w*a1i;
        si[d1] = Bq.x*a0i + Bq.y*a0r + Bq.z*a1i + Bq.w*a1r;
    }
}

// Local controlled Rot (control & target both local bits)
template<int CMASK, int TMASK>
__device__ __forceinline__ void crotL(float* sr, float* si, float4 A, float4 Bq)
{
    #pragma unroll
    for (int d0 = 0; d0 < 32; ++d0) {
        if (!(d0 & CMASK) || (d0 & TMASK)) continue;
        const int d1 = d0 | TMASK;
        float a0r = sr[d0], a0i = si[d0];
        float a1r = sr[d1], a1i = si[d1];
        sr[d0] = A.x*a0r - A.y*a0i + A.z*a1r - A.w*a1i;
        si[d0] = A.x*a0i + A.y*a0r + A.z*a1i + A.w*a1r;
        sr[d1] = Bq.x*a0r - Bq.y*a0i + Bq.z*a1r - Bq.w*a1i;
        si[d1] = Bq.x*a0i + Bq.y*a0r + Bq.z*a1i + Bq.w*a1r;
    }
}

// ---------- sim: 2 threads per circuit (h = state bit 5); block = 1 patch ----------
// NOTE: no min-waves arg — R5's (128,4) forced VGPR=64 and spilled ~100MB.

__global__ __launch_bounds__(128) void sim_kernel(
    const float* __restrict__ x,      // [B,14,14,14]
    const float* __restrict__ theta,  // [NF,1,6,3]
    float* __restrict__ feats,        // [B][NF][PP][NQ]
    float* __restrict__ ip2)          // [PP][2]
{
    const int p = blockIdx.x;
    const int t = threadIdx.x;        // 128 threads = 2 waves
    const int w = t >> 6;
    const int lane = t & 63;
    const int b = t >> 3;             // 0..15
    const int f = (lane >> 1) & 3;
    const int h = lane & 1;           // state bit 5

    __shared__ __align__(16) float scrot[NF*NQ][8];
    __shared__ __align__(16) float scomp[BB][NQ][4];   // composed enc columns

    if (t < NF*NQ) {
        const float* a = theta + t*3;
        float s, c, sap, cap, sam, cam;
        __sincosf(0.5f*a[1], &s, &c);
        __sincosf(0.5f*(a[0]+a[2]), &sap, &cap);
        __sincosf(0.5f*(a[0]-a[2]), &sam, &cam);
        scrot[t][0] =  cap*c; scrot[t][1] = -sap*c;
        scrot[t][2] = -cam*s; scrot[t][3] = -sam*s;
        scrot[t][4] =  cam*s; scrot[t][5] = -sam*s;
        scrot[t][6] =  cap*c; scrot[t][7] =  sap*c;
    }

    const int px = p/(NSIDE*NSIDE), py = (p/NSIDE)%NSIDE, pz = p%NSIDE;

    // Setup: 96 threads each build one composed encoding column (b2, q).
    // Qubit q: gate q (and gate q+6 if q<3, applied second) — commuting qubits.
    if (t < BB*NQ) {
        const int b2 = t / NQ, q = t % NQ;
        const float* xp = x + (size_t)b2*GG3 + px*GG2 + py*GG + pz;
        #define SPV(i) xp[((i)/9)*GG2 + (((i)/3)%3)*GG + ((i)%3)]
        float c0r, c0i, c1r, c1i;
        rotcol(SPV(3*q), SPV(3*q+1), SPV(3*q+2), c0r, c0i, c1r, c1i);
        if (q < 3) {
            const int k2 = 3*(q+6);
            float s_,c_,sap_,cap_,sam_,cam_;
            __sincosf(0.5f*SPV(k2+1), &s_, &c_);
            __sincosf(0.5f*(SPV(k2)+SPV(k2+2)), &sap_, &cap_);
            __sincosf(0.5f*(SPV(k2)-SPV(k2+2)), &sam_, &cam_);
            float b00r=cap_*c_, b00i=-sap_*c_, b01r=-cam_*s_, b01i=-sam_*s_;
            float b10r=cam_*s_, b10i=-sam_*s_, b11r=cap_*c_,  b11i= sap_*c_;
            float n0r = b00r*c0r - b00i*c0i + b01r*c1r - b01i*c1i;
            float n0i = b00r*c0i + b00i*c0r + b01r*c1i + b01i*c1r;
            float n1r = b10r*c0r - b10i*c0i + b11r*c1r - b11i*c1i;
            float n1i = b10r*c0i + b10i*c0r + b11r*c1i + b11i*c1r;
            c0r=n0r; c0i=n0i; c1r=n1r; c1i=n1i;
        }
        #undef SPV
        scomp[b2][q][0]=c0r; scomp[b2][q][1]=c0i;
        scomp[b2][q][2]=c1r; scomp[b2][q][3]=c1i;
    }
    __syncthreads();

    float sr[32], si[32];

    // ---- encoding from composed columns (input |0>):
    // qubit0 -> bit5 = h (select column entry); qubits 1..5 -> local spreads.
    {
        float4 C = *(const float4*)&scomp[b][0][0];
        sr[0] = h ? C.z : C.x;
        si[0] = h ? C.w : C.y;
    }
    #define ENC(Q, MASK) { \
        float4 C = *(const float4*)&scomp[b][Q][0]; \
        spreadL<MASK>(sr, si, C.x, C.y, C.z, C.w); }
    ENC(1, 16) ENC(2, 8) ENC(3, 4) ENC(4, 2) ENC(5, 1)
    #undef ENC

    // ---- CRot layer for feature f: control qubit i -> target qubit (i+1)%6
    // CR0: ctrl bit5(h), tgt local 16: only h=1 lanes apply (local gate)
    {
        float4 A  = *(const float4*)&scrot[f*NQ + 0][0];
        float4 Bq = *(const float4*)&scrot[f*NQ + 0][4];
        if (h) gate1L<16>(sr, si, A, Bq);
    }
    // CR1..CR4: fully local
    #define CRL(I, CM, TM) { \
        float4 A  = *(const float4*)&scrot[f*NQ + (I)][0]; \
        float4 Bq = *(const float4*)&scrot[f*NQ + (I)][4]; \
        crotL<CM, TM>(sr, si, A, Bq); }
    CRL(1, 16, 8) CRL(2, 8, 4) CRL(3, 4, 2) CRL(4, 2, 1)
    #undef CRL
    // CR5: ctrl local bit0, tgt bit5(h): cross-pair exchange with lane^1
    {
        float4 A  = *(const float4*)&scrot[f*NQ + 5][0];
        float4 Bq = *(const float4*)&scrot[f*NQ + 5][4];
        float cAr = h ? Bq.z : A.x, cAi = h ? Bq.w : A.y;   // coef on own amp
        float cBr = h ? Bq.x : A.z, cBi = h ? Bq.y : A.w;   // coef on partner
        #pragma unroll
        for (int d = 1; d < 32; d += 2) {
            float pr_ = __shfl_xor(sr[d], 1);
            float pi_ = __shfl_xor(si[d], 1);
            float nr = cAr*sr[d] - cAi*si[d] + cBr*pr_ - cBi*pi_;
            float ni = cAr*si[d] + cAi*sr[d] + cBr*pi_ + cBi*pr_;
            sr[d] = nr; si[d] = ni;
        }
    }

    // ---- probabilities overwrite sr (si dead)
    #pragma unroll
    for (int d = 0; d < 32; ++d) sr[d] = sr[d]*sr[d] + si[d]*si[d];

    // ---- loss pair-dots: f-partners at lane^2,^4,^6 (same h), combine over h
    float lsum = 0.f;
    #pragma unroll
    for (int xm = 2; xm <= 6; xm += 2) {
        float partial = 0.f;
        #pragma unroll
        for (int d = 0; d < 32; ++d)
            partial += sr[d] * __shfl_xor(sr[d], xm);
        float dot = partial + __shfl_xor(partial, 1);
        lsum += dot*dot;
    }
    #pragma unroll
    for (int m = 1; m < 64; m <<= 1) lsum += __shfl_xor(lsum, m);
    if (lane == 0) ip2[p*2 + w] = lsum;

    // ---- expvals: local signed tree (qubits 5..1), then h-combine; qubit0 from h
    float ev[NQ];
    #pragma unroll
    for (int lvl = 0; lvl < 5; ++lvl) {
        const int n = 32 >> (lvl + 1);
        float diff = 0.f;
        #pragma unroll
        for (int i = 0; i < n; ++i) diff += sr[2*i] - sr[2*i+1];
        ev[5 - lvl] = diff;
        #pragma unroll
        for (int i = 0; i < n; ++i) sr[i] = sr[2*i] + sr[2*i+1];
    }
    ev[0] = h ? -sr[0] : sr[0];
    #pragma unroll
    for (int q = 0; q < NQ; ++q) ev[q] += __shfl_xor(ev[q], 1);

    float* fo = feats + (((size_t)b*NF + f)*PP + p)*NQ + 3*h;
    fo[0] = ev[3*h]; fo[1] = ev[3*h+1]; fo[2] = ev[3*h+2];
}

// ---------- logits phase A: K-split, W read once ----------

__global__ __launch_bounds__(128) void logitsA(
    const float* __restrict__ feats,   // [BB][FEAT_LEN]
    const float* __restrict__ W,       // [NC][FEAT_LEN]
    float* __restrict__ partial)       // [NC][BB][NCHUNK]
{
    const int chunk = blockIdx.x;      // 0..80
    const int ctile = blockIdx.y;      // 0..4
    const int t = threadIdx.x;         // 128
    const int jbase = chunk * KCH;

    __shared__ __align__(16) float fs[BB][KCH + 4];

    #pragma unroll
    for (int i = 0; i < 16; ++i) {
        const int gi = i*128 + t;
        const int br = gi >> 7;
        const int c4 = gi & 127;
        float4 v = *(const float4*)(feats + (size_t)br*FEAT_LEN + jbase + c4*4);
        *(float4*)&fs[br][c4*4] = v;
    }
    __syncthreads();

    const int cl = t >> 4, b = t & 15;
    const int c = ctile*8 + cl;
    const float* wr = W + (size_t)c*FEAT_LEN + jbase;
    float acc = 0.f;
    #pragma unroll 8
    for (int j4 = 0; j4 < KCH/4; ++j4) {
        float4 wv = *(const float4*)(wr + j4*4);
        float4 fv = *(const float4*)&fs[b][j4*4];
        acc += wv.x*fv.x + wv.y*fv.y + wv.z*fv.z + wv.w*fv.w;
    }
    partial[((size_t)c*BB + b)*NCHUNK + chunk] = acc;
}

// ---------- phase B: logits reduce + bias, and loss reduce ----------

__global__ __launch_bounds__(768) void finalize_kernel(
    const float* __restrict__ partial, const float* __restrict__ bias,
    const float* __restrict__ ip2, float* __restrict__ out)
{
    const int t = threadIdx.x;
    if (t < BB*NC) {
        const int b = t / NC, c = t % NC;
        const float* pp = partial + ((size_t)c*BB + b)*NCHUNK;
        float acc = bias[c];
        #pragma unroll 27
        for (int i = 0; i < NCHUNK; ++i) acc += pp[i];
        out[t] = acc;
    } else if (t >= 704) {
        const int lane = t - 704;
        float acc = 0.f;
        for (int i = lane; i < PP*2; i += 64) acc += ip2[i];
        #pragma unroll
        for (int m = 1; m < 64; m <<= 1) acc += __shfl_xor(acc, m);
        if (lane == 0)   // extra /2: each unordered dot counted once per h-lane
            out[BB*NC] = acc * (LAM / (float)(NF*(NF-1)) / (float)BB * 0.5f);
    }
}

extern "C" void kernel_launch(void* const* d_in, const int* in_sizes, int n_in,
                              void* d_out, int out_size, void* d_ws, size_t ws_size,
                              hipStream_t stream) {
    const float* x     = (const float*)d_in[0];  // [16,14,14,14]
    const float* theta = (const float*)d_in[1];  // [4,1,6,3]
    const float* W     = (const float*)d_in[2];  // [40,41472]
    const float* bias  = (const float*)d_in[3];  // [40]
    float* out = (float*)d_out;                  // [640 logits][1 loss]

    float* feats   = (float*)d_ws;                       // BB*FEAT_LEN
    float* ip2     = feats + (size_t)BB * FEAT_LEN;      // PP*2
    float* partial = ip2 + (size_t)PP * 2;               // NC*BB*NCHUNK

    sim_kernel<<<PP, 128, 0, stream>>>(x, theta, feats, ip2);
    logitsA<<<dim3(NCHUNK, CTILES), 128, 0, stream>>>(feats, W, partial);
    finalize_kernel<<<1, 768, 0, stream>>>(partial, bias, ip2, out);
}